// Round 10
// baseline (1413.664 us; speedup 1.0000x reference)
//
#include <hip/hip_runtime.h>

// Problem constants
constexpr int Bz = 512;   // batch
constexpr int Tz = 256;   // seq len
constexpr int Hz = 256;   // hidden
constexpr int Pz = 14;    // predict dim
constexpr int GB = 32;    // batch groups
constexpr int GS = 8;     // hidden slices per group
constexpr int BT = 16;    // batch per group (512/32)
constexpr int KP = 264;   // LDS row stride (shorts) for w_hh1 / head staging
constexpr int XS = 260;   // x LDS row stride (floats)

typedef short s8v __attribute__((ext_vector_type(8)));
typedef float f4v __attribute__((ext_vector_type(4)));
typedef unsigned long long u64;

__device__ __forceinline__ short f2bf(float f) {
  unsigned u = __float_as_uint(f);
  u = (u + 0x7fffu + ((u >> 16) & 1u)) >> 16;   // RNE
  return (short)u;
}
__device__ __forceinline__ float bf2f(short s) {
  return __uint_as_float(((unsigned)(unsigned short)s) << 16);
}
__device__ __forceinline__ float sigm(float v) { return 1.0f / (1.0f + __expf(-v)); }
__device__ __forceinline__ float tanh_f(float v) { return 1.0f - 2.0f / (__expf(2.0f * v) + 1.0f); }

__device__ __forceinline__ u64 llc_load64(const u64* p) {
  return __hip_atomic_load(p, __ATOMIC_RELAXED, __HIP_MEMORY_SCOPE_AGENT);
}
__device__ __forceinline__ unsigned llc_load32(const unsigned* p) {
  return __hip_atomic_load(p, __ATOMIC_RELAXED, __HIP_MEMORY_SCOPE_AGENT);
}
__device__ __forceinline__ void llc_store32(unsigned* p, unsigned v) {
  __hip_atomic_store(p, v, __ATOMIC_RELAXED, __HIP_MEMORY_SCOPE_AGENT);
}
// Drain all outstanding vector-memory ops (incl. sc1 stores -> visible at LLC,
// the R5/R9-proven ordering point) without a block barrier.
__device__ __forceinline__ void drain_vm() {
  asm volatile("s_waitcnt vmcnt(0)" ::: "memory");
}

// Combined per-group flag poll: fb[0..15] = h0 wave-flags, fb[16..31] = h1
// wave-flags. Lane idx = lane&31 polls one flag; pass when ALL lanes see
// flag >= expected (e0 for h0, e1 for h1). Signed compare (trivial at t<1).
__device__ __forceinline__ void poll2(const unsigned* fb, int lane, int e0, int e1) {
  int idx = lane & 31;
  const unsigned* p = fb + idx;
  int expd = (idx < 16) ? e0 : e1;
  int f = (int)llc_load32(p);
  while (__ballot(f >= expd) != ~0ull) {
    __builtin_amdgcn_s_sleep(1);
    f = (int)llc_load32(p);
  }
}

// R10: wave-specialized, barrier-free recurrence.
//  - Mailbox word layout (R5-proven) doubles as the MFMA B-fragment layout, so
//    consumers load B-frags DIRECTLY from global (16 u64/lane) -- no LDS
//    staging, no in-loop __syncthreads.
//  - Waves 0-1: h0 recurrence only (L0, 4 m-tiles/wave, 32 MFMA).
//    Waves 2-3: L1 (w_ih1 regs + w_hh1 LDS, 64 MFMA/wave), rides 1-2 steps
//    of slack behind h0.
//  - Per-WAVE completion flags: stores -> s_waitcnt vmcnt(0) -> lane0 flag.
//  - Poll invariants (trace-verified): L0@t: f0>=t, f1>=t-1; L1@t: f0>=t+1,
//    f1>=t. Overwrite safety is implied by the poll each overwriter performs.
__global__ void __launch_bounds__(256, 1)
lstm2(const float* __restrict__ x,
      const float* __restrict__ w_ih0, const float* __restrict__ w_hh0,
      const float* __restrict__ b_ih0, const float* __restrict__ b_hh0,
      const float* __restrict__ w_ih1, const float* __restrict__ w_hh1,
      const float* __restrict__ b_ih1, const float* __restrict__ b_hh1,
      const float* __restrict__ w_lin, const float* __restrict__ b_lin,
      float* __restrict__ out,
      unsigned* __restrict__ h0g, unsigned* __restrict__ h1g,
      unsigned* __restrict__ flags)
{
  const int blk  = blockIdx.x;
  const int g    = blk >> 3;      // batch group (32)
  const int sl   = blk & 7;       // hidden slice (8)
  const int tid  = threadIdx.x;
  const int w    = tid >> 6;      // wave
  const int lane = tid & 63;
  const int q    = lane >> 4;
  const int l15  = lane & 15;     // batch within group
  const int gbase = g * BT;
  const int W    = w & 1;         // position within path (L0: w<2, L1: w>=2)

  extern __shared__ char smem_raw[];
  short* w1l = (short*)smem_raw;          // [128][KP] w_hh1 slice, kpos order
  float* xls = (float*)(w1l + 128 * KP);  // [BT][XS] x preload
  float* wls = xls + BT * XS;             // [Pz][256] w_lin permuted (head)
  short* hst = (short*)(wls + Pz * Hz);   // [BT][KP] head staging

  // ---- one-time: A-fragments for this wave's 4 m-tiles ----
  // tiles tset = {2W, 2W+1, 2W+4, 2W+5}; rows rr = t*16+l15, rr = unit*4+gate;
  // A elem j <-> ktrue = kt*32 + q*4 + (j>>1) + 16*(j&1) (kpos permutation).
  s8v WfA[4][8];    // L0 waves: w_hh0; L1 waves: w_ih1
  {
    const float* wsrc = (w < 2) ? w_hh0 : w_ih1;
    #pragma unroll
    for (int j4 = 0; j4 < 4; ++j4) {
      int t = 2 * W + (j4 & 1) + (j4 >> 1) * 4;          // {2W,2W+1,2W+4,2W+5}
      int rr = t * 16 + l15;
      int grow = (rr & 3) * Hz + sl * 32 + (rr >> 2);
      const float* p = wsrc + (size_t)grow * Hz;
      #pragma unroll
      for (int kt = 0; kt < 8; ++kt) {
        s8v f;
        #pragma unroll
        for (int j = 0; j < 8; ++j) {
          int ktrue = kt * 32 + q * 4 + (j >> 1) + 16 * (j & 1);
          f[j] = f2bf(p[ktrue]);
        }
        WfA[j4][kt] = f;
      }
    }
  }
  // ---- w_hh1 -> LDS in kpos order (all 4 waves cooperate) ----
  for (int i = tid; i < 128 * 256; i += 256) {
    int r = i >> 8, kpos = i & 255;
    int grow = (r & 3) * Hz + sl * 32 + (r >> 2);
    int kt = kpos >> 5, rem = kpos & 31, q2 = rem >> 3, j = rem & 7;
    int ktrue = kt * 32 + q2 * 4 + (j >> 1) + 16 * (j & 1);
    w1l[r * KP + kpos] = f2bf(w_hh1[(size_t)grow * Hz + ktrue]);
  }
  // per-lane epilogue constants: unit u[j4] = tset[j4]*4 + q, gates r=0..3
  float wih[4][4], bia[4][4];
  #pragma unroll
  for (int j4 = 0; j4 < 4; ++j4) {
    int t = 2 * W + (j4 & 1) + (j4 >> 1) * 4;
    int u = t * 4 + q;
    #pragma unroll
    for (int r = 0; r < 4; ++r) {
      int gi = r * Hz + sl * 32 + u;
      if (w < 2) { wih[j4][r] = w_ih0[gi]; bia[j4][r] = b_ih0[gi] + b_hh0[gi]; }
      else       { wih[j4][r] = 0.f;       bia[j4][r] = b_ih1[gi] + b_hh1[gi]; }
    }
  }
  float cc[4] = {0.f, 0.f, 0.f, 0.f};   // cell states (4 units/lane)

  // ---- preload x (L0 waves read it) and permuted w_lin (head) ----
  for (int i = tid; i < BT * (Tz / 4); i += 256) {
    int b = i >> 6, c4 = i & 63;
    f4v v = *(const f4v*)(x + (size_t)(gbase + b) * Tz + c4 * 4);
    *(f4v*)(xls + b * XS + c4 * 4) = v;
  }
  if (sl == 0) {
    for (int i = tid; i < Pz * Hz; i += 256) {
      int p = i >> 8, kpos = i & 255;
      int sl2 = kpos >> 5, w2 = (kpos >> 3) & 3, q2 = (kpos >> 1) & 3, jj = kpos & 1;
      wls[i] = w_lin[p * Hz + sl2 * 32 + w2 * 4 + q2 + 16 * jj];
    }
  }
  __syncthreads();   // LDS (w1l, xls, wls) ready; last barrier before head

  const unsigned* fb = flags + g * 64;        // [0..15] h0-flags, [16..31] h1-flags
  // B-frag load base (u64 index): frag kt at words (kt*4+q)*2048 + batch*4 + {0..3}
  const size_t fragbase = (size_t)q * 1024 + (size_t)(gbase + l15) * 2;
  // store words: (sl*4 + 2W + wi)*2048 + (gbase+l15)*4 + q, wi in {0,1}
  const size_t st0 = (size_t)(sl * 4 + 2 * W) * 2048 + (size_t)(gbase + l15) * 4 + q;
  const size_t st1 = st0 + 2048;

  if (w < 2) {
    // ================= L0 path: the h0 recurrence =================
    unsigned* myflag = flags + g * 64 + sl * 2 + W;
    for (int t = 0; t < Tz; ++t) {
      poll2(fb, lane, t, t - 1);
      // load h0[t-1] B-frags, parity (t+1)&1
      const u64* src = (const u64*)h0g + (size_t)((t + 1) & 1) * 32768;
      u64 lo[8], hi[8];
      #pragma unroll
      for (int kt = 0; kt < 8; ++kt) {
        size_t a = fragbase + (size_t)kt * 4096;
        lo[kt] = llc_load64(src + a);
        hi[kt] = llc_load64(src + a + 1);
      }
      f4v acc[4] = {{0,0,0,0},{0,0,0,0},{0,0,0,0},{0,0,0,0}};
      #pragma unroll
      for (int kt = 0; kt < 8; ++kt) {
        union { u64 d[2]; s8v v; } hv;
        hv.d[0] = lo[kt]; hv.d[1] = hi[kt];
        #pragma unroll
        for (int j4 = 0; j4 < 4; ++j4)
          acc[j4] = __builtin_amdgcn_mfma_f32_16x16x32_bf16(WfA[j4][kt], hv.v, acc[j4], 0, 0, 0);
      }
      float xv = xls[l15 * XS + t];
      float hh[4];
      #pragma unroll
      for (int j4 = 0; j4 < 4; ++j4) {
        float iv = sigm  (acc[j4][0] + xv * wih[j4][0] + bia[j4][0]);
        float fv = sigm  (acc[j4][1] + xv * wih[j4][1] + bia[j4][1]);
        float gv = tanh_f(acc[j4][2] + xv * wih[j4][2] + bia[j4][2]);
        float ov = sigm  (acc[j4][3] + xv * wih[j4][3] + bia[j4][3]);
        cc[j4] = fv * cc[j4] + iv * gv;
        hh[j4] = ov * tanh_f(cc[j4]);
      }
      unsigned* dst = h0g + (size_t)(t & 1) * 65536;
      unsigned pkA = (unsigned)(unsigned short)f2bf(hh[0])
                   | ((unsigned)(unsigned short)f2bf(hh[2]) << 16);
      unsigned pkB = (unsigned)(unsigned short)f2bf(hh[1])
                   | ((unsigned)(unsigned short)f2bf(hh[3]) << 16);
      llc_store32(dst + st0, pkA);
      llc_store32(dst + st1, pkB);
      drain_vm();
      if (lane == 0) llc_store32(myflag, (unsigned)(t + 1));
    }
  } else {
    // ================= L1 path: rides h0's slack =================
    unsigned* myflag = flags + g * 64 + 16 + sl * 2 + W;
    const short* whbase = w1l + l15 * KP + q * 8;   // + tset[j4]*16*KP + kt*32
    #pragma unroll
    for (int dummy = 0; dummy < 1; ++dummy) {}      // (keep structure flat)
    for (int t = 0; t < Tz; ++t) {
      poll2(fb, lane, t + 1, t);
      // h0[t] parity t&1; h1[t-1] parity (t+1)&1
      const u64* s0 = (const u64*)h0g + (size_t)(t & 1) * 32768;
      const u64* s1 = (const u64*)h1g + (size_t)((t + 1) & 1) * 32768;
      u64 lo0[8], hi0[8], lo1[8], hi1[8];
      #pragma unroll
      for (int kt = 0; kt < 8; ++kt) {
        size_t a = fragbase + (size_t)kt * 4096;
        lo0[kt] = llc_load64(s0 + a);
        hi0[kt] = llc_load64(s0 + a + 1);
        lo1[kt] = llc_load64(s1 + a);
        hi1[kt] = llc_load64(s1 + a + 1);
      }
      f4v acc[4] = {{0,0,0,0},{0,0,0,0},{0,0,0,0},{0,0,0,0}};
      #pragma unroll
      for (int kt = 0; kt < 8; ++kt) {
        union { u64 d[2]; s8v v; } h0v, h1v;
        h0v.d[0] = lo0[kt]; h0v.d[1] = hi0[kt];
        h1v.d[0] = lo1[kt]; h1v.d[1] = hi1[kt];
        #pragma unroll
        for (int j4 = 0; j4 < 4; ++j4) {
          int t4 = 2 * W + (j4 & 1) + (j4 >> 1) * 4;
          s8v wh = *(const s8v*)(whbase + (t4 * 16) * KP + kt * 32);
          acc[j4] = __builtin_amdgcn_mfma_f32_16x16x32_bf16(WfA[j4][kt], h0v.v, acc[j4], 0, 0, 0);
          acc[j4] = __builtin_amdgcn_mfma_f32_16x16x32_bf16(wh, h1v.v, acc[j4], 0, 0, 0);
        }
      }
      float hh[4];
      #pragma unroll
      for (int j4 = 0; j4 < 4; ++j4) {
        float iv = sigm  (acc[j4][0] + bia[j4][0]);
        float fv = sigm  (acc[j4][1] + bia[j4][1]);
        float gv = tanh_f(acc[j4][2] + bia[j4][2]);
        float ov = sigm  (acc[j4][3] + bia[j4][3]);
        cc[j4] = fv * cc[j4] + iv * gv;
        hh[j4] = ov * tanh_f(cc[j4]);
      }
      unsigned* dst = h1g + (size_t)(t & 1) * 65536;
      unsigned pkA = (unsigned)(unsigned short)f2bf(hh[0])
                   | ((unsigned)(unsigned short)f2bf(hh[2]) << 16);
      unsigned pkB = (unsigned)(unsigned short)f2bf(hh[1])
                   | ((unsigned)(unsigned short)f2bf(hh[3]) << 16);
      llc_store32(dst + st0, pkA);
      llc_store32(dst + st1, pkB);
      drain_vm();
      if (lane == 0) llc_store32(myflag, (unsigned)(t + 1));
    }
  }

  // ---- final head (sl==0 blocks, all 4 waves): out = h1[T-1] @ w_lin^T + b ----
  if (sl == 0) {
    poll2(fb, lane, Tz, Tz);   // flags0 also reaches Tz; flags1 >= Tz is the need
    const u64* s1 = (const u64*)h1g + (size_t)((Tz - 1) & 1) * 32768;
    for (int k = 0; k < 4; ++k) {
      int i = tid + k * 256;
      int c = i & 1, b = (i >> 1) & 15, slw = i >> 5;
      u64 v = llc_load64(s1 + ((size_t)slw * Bz + gbase + b) * 2 + c);
      *(u64*)(hst + b * KP + slw * 8 + c * 4) = v;
    }
    __syncthreads();
    for (int i = tid; i < BT * Pz; i += 256) {
      int b = i / Pz, p = i - b * Pz;
      const float* wr = wls + p * Hz;
      float acc = b_lin[p];
      for (int kk = 0; kk < Hz; ++kk)
        acc += bf2f(hst[b * KP + kk]) * wr[kk];   // both in kpos order
      out[(gbase + b) * Pz + p] = acc;
    }
  }
}

extern "C" void kernel_launch(void* const* d_in, const int* in_sizes, int n_in,
                              void* d_out, int out_size, void* d_ws, size_t ws_size,
                              hipStream_t stream) {
  const float* x     = (const float*)d_in[0];
  const float* w_ih0 = (const float*)d_in[1];
  const float* w_hh0 = (const float*)d_in[2];
  const float* b_ih0 = (const float*)d_in[3];
  const float* b_hh0 = (const float*)d_in[4];
  const float* w_ih1 = (const float*)d_in[5];
  const float* w_hh1 = (const float*)d_in[6];
  const float* b_ih1 = (const float*)d_in[7];
  const float* b_hh1 = (const float*)d_in[8];
  const float* w_lin = (const float*)d_in[9];
  const float* b_lin = (const float*)d_in[10];
  float* out = (float*)d_out;

  unsigned char* ws = (unsigned char*)d_ws;
  unsigned* h0g   = (unsigned*)ws;                     // [2][65536] u32
  unsigned* h1g   = (unsigned*)(ws + (512 << 10));     // [2][65536] u32
  unsigned* flags = (unsigned*)(ws + (1024 << 10));    // [32 groups][64] u32
  // memset(0): h zeros (initial states) + all flags 0 ("0 steps done").
  hipMemsetAsync(d_ws, 0, (1024 << 10) + 16384, stream);

  size_t lds_bytes = (size_t)128 * KP * 2        // w_hh1
                   + (size_t)(BT * XS) * 4       // x preload
                   + (size_t)(Pz * Hz) * 4       // permuted w_lin (head)
                   + (size_t)BT * KP * 2;        // head staging
  hipFuncSetAttribute((const void*)lstm2,
                      hipFuncAttributeMaxDynamicSharedMemorySize, (int)lds_bytes);
  lstm2<<<GB * GS, 256, lds_bytes, stream>>>(x, w_ih0, w_hh0, b_ih0, b_hh0,
                                             w_ih1, w_hh1, b_ih1, b_hh1,
                                             w_lin, b_lin, out, h0g, h1g, flags);
}